// Round 2
// baseline (5095.652 us; speedup 1.0000x reference)
//
#include <hip/hip_runtime.h>
#include <hip/hip_bf16.h>
#include <stdint.h>

#define T_STEPS 512
#define BATCH   64
#define IN_DIM  512
#define H_DIM   1024
#define KDIM    1536   // H + IN

typedef float  f32x4  __attribute__((ext_vector_type(4)));
typedef short  short8 __attribute__((ext_vector_type(8)));
typedef __bf16 bf16x8 __attribute__((ext_vector_type(8)));

__device__ __forceinline__ short f2bf(float f) {
    union { float f; unsigned u; } x; x.f = f;
    unsigned r = (x.u + 0x7fffu + ((x.u >> 16) & 1u)) >> 16;
    return (short)r;
}

// Pack W[g] (fp32, [1024][1536] row-major) into bf16 MFMA B-fragment order:
// frag slot = ((c*4+g)*48 + s), within slot lane l = grp*16 + r holds
// W[g][c*16 + r][s*32 + grp*8 + u], u = 0..7  (16 B per lane, coalesced loads).
__global__ __launch_bounds__(256) void pack_w_kernel(const float* __restrict__ W,
                                                     short* __restrict__ Wpk, int g) {
    int e = blockIdx.x * 256 + threadIdx.x;      // e < 1024*1536
    int j = e / KDIM, k = e - j * KDIM;
    short v = f2bf(W[e]);
    int c = j >> 4, r = j & 15, s = k >> 5, grp = (k & 31) >> 3, u = k & 7;
    int slot = ((c * 4 + g) * 48 + s) * 64 + grp * 16 + r;
    Wpk[(size_t)slot * 8 + u] = v;
}

__global__ __launch_bounds__(256) void init_state_kernel(short* hb0, float* cbuf) {
    int e = blockIdx.x * 256 + threadIdx.x;      // e < 65536
    hb0[e] = 0; cbuf[e] = 0.f;
}

// One timestep. Grid 256 = 4 batch-tiles x 64 col-tiles. Block: 16 batch x 16 cols,
// 4 waves = 4 gates (f,i,c,o), K = 1536 (h part k<1024, x part k>=1024).
__global__ __launch_bounds__(256) void lstm_step_kernel(
    const short* __restrict__ Wpk, const float* __restrict__ x,
    const short* __restrict__ hprev, short* __restrict__ hnext,
    float* __restrict__ cbuf, float* __restrict__ out_t,
    const float* __restrict__ bf_, const float* __restrict__ bi_,
    const float* __restrict__ bc_, const float* __restrict__ bo_, int t)
{
    // hx tile, 16 rows x 192 16B-slots, XOR-swizzled (slot' = k16 ^ (row&7)) so the
    // stride-384B A-frag column read spreads evenly over all 32 banks.
    __shared__ short smA[16 * 192 * 8];   // 48 KB
    __shared__ float smZ[4 * 16 * 16];    // 4 KB gate pre-activations

    const int tid = threadIdx.x;
    const int w = tid >> 6, lane = tid & 63;
    const int bt = blockIdx.x & 3, cb = blockIdx.x >> 2;
    const int b0 = bt * 16;

    // ---- stage h part (bf16, 2048 slots) ----
    #pragma unroll
    for (int q = 0; q < 8; ++q) {
        int sl = q * 256 + tid;               // sl < 2048
        int row = sl >> 7, k16 = sl & 127;
        short8 v = *reinterpret_cast<const short8*>(hprev + (size_t)(b0 + row) * H_DIM + k16 * 8);
        *reinterpret_cast<short8*>(&smA[((row * 192) + (k16 ^ (row & 7))) * 8]) = v;
    }
    // ---- stage x part (fp32 -> bf16, 1024 slots) ----
    const float* xt = x + ((size_t)t * BATCH + b0) * IN_DIM;
    #pragma unroll
    for (int q = 0; q < 4; ++q) {
        int sl = q * 256 + tid;               // sl < 1024
        int row = sl >> 6, kk = sl & 63;
        int k16 = 128 + kk;
        const float* xp = xt + (size_t)row * IN_DIM + kk * 8;
        short8 v;
        #pragma unroll
        for (int u = 0; u < 8; ++u) v[u] = f2bf(xp[u]);
        *reinterpret_cast<short8*>(&smA[((row * 192) + (k16 ^ (row & 7))) * 8]) = v;
    }
    __syncthreads();

    // ---- MFMA: gate g = w, 16x16 tile, K = 1536 ----
    const int r = lane & 15, hi = lane >> 4;
    const int g = w;
    const short* wgp = Wpk + (size_t)((cb * 4 + g) * 48) * 512 + lane * 8;
    f32x4 acc = {0.f, 0.f, 0.f, 0.f};
    #pragma unroll 4
    for (int s = 0; s < 48; ++s) {
        int k16 = s * 4 + hi;
        short8 a = *reinterpret_cast<const short8*>(&smA[((r * 192) + (k16 ^ (r & 7))) * 8]);
        short8 b = *reinterpret_cast<const short8*>(wgp + (size_t)s * 512);
        acc = __builtin_amdgcn_mfma_f32_16x16x32_bf16(
            __builtin_bit_cast(bf16x8, a), __builtin_bit_cast(bf16x8, b), acc, 0, 0, 0);
    }
    // C layout (m89-verified): col = lane&15, row = (lane>>4)*4 + i
    #pragma unroll
    for (int i = 0; i < 4; ++i)
        smZ[(g * 16 + (hi * 4 + i)) * 16 + r] = acc[i];
    __syncthreads();

    // ---- elementwise gates: thread -> (row, col) of the 16x16 tile ----
    int row = tid >> 4, col = tid & 15;
    int b = b0 + row, j = cb * 16 + col;
    float zf = smZ[(0 * 16 + row) * 16 + col] + bf_[j];
    float zi = smZ[(1 * 16 + row) * 16 + col] + bi_[j];
    float zc = smZ[(2 * 16 + row) * 16 + col] + bc_[j];
    float zo = smZ[(3 * 16 + row) * 16 + col] + bo_[j];
    float fg = 1.f / (1.f + __expf(-zf));
    float ig = 1.f / (1.f + __expf(-zi));
    float cg = 2.f / (1.f + __expf(-2.f * zc)) - 1.f;
    float og = 1.f / (1.f + __expf(-zo));
    size_t idx = (size_t)b * H_DIM + j;
    float nc = fg * cbuf[idx] + ig * cg;
    float nh = og * (2.f / (1.f + __expf(-2.f * nc)) - 1.f);
    cbuf[idx]  = nc;
    hnext[idx] = f2bf(nh);
    out_t[idx] = nh;
}

extern "C" void kernel_launch(void* const* d_in, const int* in_sizes, int n_in,
                              void* d_out, int out_size, void* d_ws, size_t ws_size,
                              hipStream_t stream) {
    const float* x   = (const float*)d_in[0];
    const float* Wf  = (const float*)d_in[1];
    const float* Wi  = (const float*)d_in[2];
    const float* Wc  = (const float*)d_in[3];
    const float* Wo  = (const float*)d_in[4];
    const float* bf_ = (const float*)d_in[5];
    const float* bi_ = (const float*)d_in[6];
    const float* bc_ = (const float*)d_in[7];
    const float* bo_ = (const float*)d_in[8];
    float* out = (float*)d_out;

    // ws layout: hb ping-pong (2x64x1024 bf16) | cbuf (64x1024 f32) | Wpk (12.6 MB)
    char*  ws   = (char*)d_ws;
    short* hb   = (short*)(ws);                       // 262144 B
    float* cbuf = (float*)(ws + 262144);              // 262144 B
    short* Wpk  = (short*)(ws + 524288);              // 12582912 B

    const float* Ws[4] = {Wf, Wi, Wc, Wo};
    for (int g = 0; g < 4; ++g)
        pack_w_kernel<<<(H_DIM * KDIM) / 256, 256, 0, stream>>>(Ws[g], Wpk, g);
    init_state_kernel<<<(BATCH * H_DIM) / 256, 256, 0, stream>>>(hb, cbuf);

    for (int t = 0; t < T_STEPS; ++t) {
        const short* hp = hb + (t & 1) * (BATCH * H_DIM);
        short*       hn = hb + ((t + 1) & 1) * (BATCH * H_DIM);
        lstm_step_kernel<<<256, 256, 0, stream>>>(
            Wpk, x, hp, hn, cbuf, out + (size_t)t * BATCH * H_DIM,
            bf_, bi_, bc_, bo_, t);
    }
}